// Round 1
// baseline (416.418 us; speedup 1.0000x reference)
//
#include <hip/hip_runtime.h>

// BootstrapEnsemble: M=100 MLPs (16 -> 128 -> 4x(128x128) -> {mu, log sigma}),
// shared batch N=16384. Fully fused bf16-MFMA kernel, fp32 accumulate.
//
// Block = (model m, 128-row batch tile). 4 waves, 2x2 wave grid over the
// 128(k_out) x 128(n) output tile. Swapped-operand mfma_16x16x32_bf16:
//   D[k_out][n] = sum_h W[k_out][h] * h[n][h]
// so the C-layout (lane holds 4 consecutive k for one n) matches h's
// row-major [n][h] LDS layout -> b64 epilogue writes, and both A (W) and
// B (h) fragments are 8-consecutive-h ds_read_b128 with the same XOR
// swizzle (elem ^= (row&7)<<3) to kill stride-256B bank conflicts.

typedef float  f32x4  __attribute__((ext_vector_type(4)));
typedef __bf16 bf16x8 __attribute__((ext_vector_type(8)));

union BF8 { bf16x8 v; unsigned int ui[4]; unsigned short us[8]; };

__device__ __forceinline__ unsigned int f2bf_pk(float lo, float hi) {
  // round-to-nearest-even f32 -> bf16, packed pair
  unsigned int a = __float_as_uint(lo);
  unsigned int b = __float_as_uint(hi);
  a = (a + 0x7FFFu + ((a >> 16) & 1u)) >> 16;
  b = (b + 0x7FFFu + ((b >> 16) & 1u)) >> 16;
  return a | (b << 16);
}

#define MODELS 100
#define NPT    16384
#define HDIM   128
#define SG_OFF (MODELS * NPT)

__global__ __launch_bounds__(256, 2) void ens_mlp(
    const float* __restrict__ x,
    const float* __restrict__ W1,  const float* __restrict__ b1,
    const float* __restrict__ Wh,  const float* __restrict__ bh,
    const float* __restrict__ Wmu, const float* __restrict__ bmu,
    const float* __restrict__ Wsg, const float* __restrict__ bsg,
    float* __restrict__ out)
{
  __shared__ unsigned short hbuf[HDIM * HDIM]; // [n 0..127][h 0..127] bf16, swizzled
  __shared__ unsigned short wbuf[HDIM * HDIM]; // [k_out 0..127][h 0..127] bf16, swizzled

  // XCD-chunked bijective swizzle: 12800 blocks = 8 XCDs * 1600
  const int bid = blockIdx.x;
  const int swz = (bid & 7) * 1600 + (bid >> 3);
  const int m   = swz >> 7;            // model
  const int n0  = (swz & 127) << 7;    // batch-tile base

  const int t    = threadIdx.x;
  const int lane = t & 63;
  const int wv   = t >> 6;     // wave 0..3
  const int wk   = wv & 1;     // k_out half
  const int wn   = wv >> 1;    // n half
  const int c    = lane & 15;  // frag row (A: k_out, B: n) / D col (n)
  const int g    = lane >> 4;  // frag k-group / D row group
  const int cs   = (c & 7) << 3;  // element-index xor swizzle ((row&7)<<3)

  f32x4 zf = {0.0f, 0.0f, 0.0f, 0.0f};

  // ---------------- layer 1: direct-from-global fragments (K=16 pad 32) ----
  BF8 a1[4], xb[4];
  {
    const float* W1m = W1 + m * (HDIM * 16);
    #pragma unroll
    for (int kt = 0; kt < 4; ++kt) {
      if (g < 2) {
        int row = wk * 64 + kt * 16 + c;            // k_out
        const f32x4* p = (const f32x4*)(W1m + row * 16 + g * 8);
        f32x4 u = p[0], w = p[1];
        a1[kt].ui[0] = f2bf_pk(u[0], u[1]); a1[kt].ui[1] = f2bf_pk(u[2], u[3]);
        a1[kt].ui[2] = f2bf_pk(w[0], w[1]); a1[kt].ui[3] = f2bf_pk(w[2], w[3]);
      } else {
        a1[kt].ui[0] = 0u; a1[kt].ui[1] = 0u; a1[kt].ui[2] = 0u; a1[kt].ui[3] = 0u;
      }
    }
    #pragma unroll
    for (int nt = 0; nt < 4; ++nt) {
      if (g < 2) {
        int n = n0 + wn * 64 + nt * 16 + c;
        const f32x4* p = (const f32x4*)(x + n * 16 + g * 8);
        f32x4 u = p[0], w = p[1];
        xb[nt].ui[0] = f2bf_pk(u[0], u[1]); xb[nt].ui[1] = f2bf_pk(u[2], u[3]);
        xb[nt].ui[2] = f2bf_pk(w[0], w[1]); xb[nt].ui[3] = f2bf_pk(w[2], w[3]);
      } else {
        xb[nt].ui[0] = 0u; xb[nt].ui[1] = 0u; xb[nt].ui[2] = 0u; xb[nt].ui[3] = 0u;
      }
    }
  }

  // stage loads for hidden layer 0 weights (fp32 -> regs, cvt+LDS later)
  f32x4 wst[16];
  {
    const f32x4* ws = (const f32x4*)(Wh + (size_t)m * (4 * HDIM * HDIM));
    #pragma unroll
    for (int j = 0; j < 8; ++j) {
      wst[2 * j]     = ws[2 * t + 512 * j];
      wst[2 * j + 1] = ws[2 * t + 512 * j + 1];
    }
  }

  // layer-1 bias
  f32x4 bs[4];
  #pragma unroll
  for (int kt = 0; kt < 4; ++kt)
    bs[kt] = *(const f32x4*)(b1 + m * HDIM + (wk * 4 + kt) * 16 + g * 4);

  // layer-1 MFMAs
  f32x4 acc[4][4];
  #pragma unroll
  for (int kt = 0; kt < 4; ++kt)
    #pragma unroll
    for (int nt = 0; nt < 4; ++nt)
      acc[kt][nt] = __builtin_amdgcn_mfma_f32_16x16x32_bf16(a1[kt].v, xb[nt].v, zf, 0, 0, 0);

  // layer-1 epilogue: bias+relu+cvt -> hbuf (no barrier needed before: first LDS use)
  #pragma unroll
  for (int kt = 0; kt < 4; ++kt) {
    int kbase = (wk * 4 + kt) * 16 + g * 4;
    int col   = kbase ^ cs;
    #pragma unroll
    for (int nt = 0; nt < 4; ++nt) {
      int nl = wn * 64 + nt * 16 + c;
      float v0 = fmaxf(acc[kt][nt][0] + bs[kt][0], 0.0f);
      float v1 = fmaxf(acc[kt][nt][1] + bs[kt][1], 0.0f);
      float v2 = fmaxf(acc[kt][nt][2] + bs[kt][2], 0.0f);
      float v3 = fmaxf(acc[kt][nt][3] + bs[kt][3], 0.0f);
      uint2 pk; pk.x = f2bf_pk(v0, v1); pk.y = f2bf_pk(v2, v3);
      *(uint2*)&hbuf[nl * HDIM + col] = pk;
    }
  }

  // hidden-layer-0 weights: cvt + LDS write
  {
    int rowb = t >> 4;
    int colb = (t & 15) * 8;
    int rsw  = (rowb & 7) << 3;
    int col  = colb ^ rsw;
    #pragma unroll
    for (int j = 0; j < 8; ++j) {
      int r = rowb + 16 * j;
      uint4 u;
      u.x = f2bf_pk(wst[2 * j][0],     wst[2 * j][1]);
      u.y = f2bf_pk(wst[2 * j][2],     wst[2 * j][3]);
      u.z = f2bf_pk(wst[2 * j + 1][0], wst[2 * j + 1][1]);
      u.w = f2bf_pk(wst[2 * j + 1][2], wst[2 * j + 1][3]);
      *(uint4*)&wbuf[r * HDIM + col] = u;
    }
  }
  __syncthreads();

  // ---------------- 4 hidden layers, in-place h and W (single-buffered) ----
  for (int i = 0; i < 4; ++i) {
    #pragma unroll
    for (int kt = 0; kt < 4; ++kt)
      bs[kt] = *(const f32x4*)(bh + m * 512 + i * HDIM + (wk * 4 + kt) * 16 + g * 4);

    if (i < 3) {  // prefetch next layer's weights into regs during compute
      const f32x4* ws = (const f32x4*)(Wh + (size_t)m * (4 * HDIM * HDIM) + (i + 1) * (HDIM * HDIM));
      #pragma unroll
      for (int j = 0; j < 8; ++j) {
        wst[2 * j]     = ws[2 * t + 512 * j];
        wst[2 * j + 1] = ws[2 * t + 512 * j + 1];
      }
    }

    #pragma unroll
    for (int kt = 0; kt < 4; ++kt)
      #pragma unroll
      for (int nt = 0; nt < 4; ++nt)
        acc[kt][nt] = zf;

    #pragma unroll
    for (int kc = 0; kc < 4; ++kc) {
      int col = (kc * 32 + g * 8) ^ cs;
      BF8 af[4], bf[4];
      #pragma unroll
      for (int kt = 0; kt < 4; ++kt)
        af[kt].v = *(const bf16x8*)&wbuf[(wk * 64 + kt * 16 + c) * HDIM + col];
      #pragma unroll
      for (int nt = 0; nt < 4; ++nt)
        bf[nt].v = *(const bf16x8*)&hbuf[(wn * 64 + nt * 16 + c) * HDIM + col];
      #pragma unroll
      for (int kt = 0; kt < 4; ++kt)
        #pragma unroll
        for (int nt = 0; nt < 4; ++nt)
          acc[kt][nt] = __builtin_amdgcn_mfma_f32_16x16x32_bf16(af[kt].v, bf[nt].v, acc[kt][nt], 0, 0, 0);
    }
    __syncthreads();   // all LDS reads of this layer done

    // epilogue: write h in place
    #pragma unroll
    for (int kt = 0; kt < 4; ++kt) {
      int kbase = (wk * 4 + kt) * 16 + g * 4;
      int col   = kbase ^ cs;
      #pragma unroll
      for (int nt = 0; nt < 4; ++nt) {
        int nl = wn * 64 + nt * 16 + c;
        float v0 = fmaxf(acc[kt][nt][0] + bs[kt][0], 0.0f);
        float v1 = fmaxf(acc[kt][nt][1] + bs[kt][1], 0.0f);
        float v2 = fmaxf(acc[kt][nt][2] + bs[kt][2], 0.0f);
        float v3 = fmaxf(acc[kt][nt][3] + bs[kt][3], 0.0f);
        uint2 pk; pk.x = f2bf_pk(v0, v1); pk.y = f2bf_pk(v2, v3);
        *(uint2*)&hbuf[nl * HDIM + col] = pk;
      }
    }
    if (i < 3) {  // write next layer's weights in place
      int rowb = t >> 4;
      int colb = (t & 15) * 8;
      int rsw  = (rowb & 7) << 3;
      int col  = colb ^ rsw;
      #pragma unroll
      for (int j = 0; j < 8; ++j) {
        int r = rowb + 16 * j;
        uint4 u;
        u.x = f2bf_pk(wst[2 * j][0],     wst[2 * j][1]);
        u.y = f2bf_pk(wst[2 * j][2],     wst[2 * j][3]);
        u.z = f2bf_pk(wst[2 * j + 1][0], wst[2 * j + 1][1]);
        u.w = f2bf_pk(wst[2 * j + 1][2], wst[2 * j + 1][3]);
        *(uint4*)&wbuf[r * HDIM + col] = u;
      }
    }
    __syncthreads();
  }

  // ---------------- heads: mu (row 0) and log-sigma (row 1) ----------------
  f32x4 acc2[2];
  acc2[0] = zf; acc2[1] = zf;
  #pragma unroll
  for (int kc = 0; kc < 4; ++kc) {
    int col = (kc * 32 + g * 8) ^ cs;
    BF8 hw;
    if (c < 2) {
      const float* wp = (c == 0 ? Wmu : Wsg) + m * HDIM + kc * 32 + g * 8;
      const f32x4* p = (const f32x4*)wp;
      f32x4 u = p[0], w = p[1];
      hw.ui[0] = f2bf_pk(u[0], u[1]); hw.ui[1] = f2bf_pk(u[2], u[3]);
      hw.ui[2] = f2bf_pk(w[0], w[1]); hw.ui[3] = f2bf_pk(w[2], w[3]);
    } else {
      hw.ui[0] = 0u; hw.ui[1] = 0u; hw.ui[2] = 0u; hw.ui[3] = 0u;
    }
    #pragma unroll
    for (int nt = 0; nt < 2; ++nt) {
      int nl = (wv * 2 + nt) * 16 + c;
      BF8 hf; hf.v = *(const bf16x8*)&hbuf[nl * HDIM + col];
      acc2[nt] = __builtin_amdgcn_mfma_f32_16x16x32_bf16(hw.v, hf.v, acc2[nt], 0, 0, 0);
    }
  }
  if (g == 0) {
    float bm  = bmu[m];
    float bsv = bsg[m];
    #pragma unroll
    for (int nt = 0; nt < 2; ++nt) {
      int n = n0 + (wv * 2 + nt) * 16 + c;
      out[m * NPT + n]          = acc2[nt][0] + bm;
      out[SG_OFF + m * NPT + n] = expf(acc2[nt][1] + bsv);
    }
  }
}

extern "C" void kernel_launch(void* const* d_in, const int* in_sizes, int n_in,
                              void* d_out, int out_size, void* d_ws, size_t ws_size,
                              hipStream_t stream) {
  const float* x   = (const float*)d_in[0];
  const float* W1  = (const float*)d_in[1];
  const float* b1  = (const float*)d_in[2];
  const float* Wh  = (const float*)d_in[3];
  const float* bh  = (const float*)d_in[4];
  const float* Wmu = (const float*)d_in[5];
  const float* bmu = (const float*)d_in[6];
  const float* Wsg = (const float*)d_in[7];
  const float* bsg = (const float*)d_in[8];
  (void)in_sizes; (void)n_in; (void)out_size; (void)d_ws; (void)ws_size;

  ens_mlp<<<12800, 256, 0, stream>>>(x, W1, b1, Wh, bh, Wmu, bmu, Wsg, bsg,
                                     (float*)d_out);
}

// Round 2
// 326.907 us; speedup vs baseline: 1.2738x; 1.2738x over previous
//
#include <hip/hip_runtime.h>

// BootstrapEnsemble: M=100 MLPs (16 -> 128 -> 4x(128x128) -> {mu, log sigma}),
// shared batch N=16384. Two kernels:
//  1) cvt_weights: one-shot fp32->bf16 of x/W1/Wh/Wmu/Wsig into d_ws. Wh is
//     written PRE-SWIZZLED to the exact LDS image (elem col ^= (row&7)<<3), so
//     the main kernel can stage it with global_load_lds (linear dest).
//  2) ens_mlp: fully fused MFMA MLP. Block = (model, 128-row batch tile),
//     4 waves in a 2x2 grid. Swapped-operand mfma_16x16x32_bf16 so the
//     C layout (4 consecutive k per lane) matches h's row-major LDS tile.

typedef float  f32x4  __attribute__((ext_vector_type(4)));
typedef __bf16 bf16x8 __attribute__((ext_vector_type(8)));

union BF8 { bf16x8 v; unsigned int ui[4]; unsigned short us[8]; };

__device__ __forceinline__ unsigned int f2bf_pk(float lo, float hi) {
  // round-to-nearest-even f32 -> bf16, packed pair
  unsigned int a = __float_as_uint(lo);
  unsigned int b = __float_as_uint(hi);
  a = (a + 0x7FFFu + ((a >> 16) & 1u)) >> 16;
  b = (b + 0x7FFFu + ((b >> 16) & 1u)) >> 16;
  return a | (b << 16);
}

#define MODELS 100
#define NPT    16384
#define HDIM   128
#define SG_OFF (MODELS * NPT)

// d_ws layout (bf16 element offsets)
#define XB_OFF   0                       // x:    16384 x 16          = 262144
#define W1B_OFF  262144                  // W1:   100 x 128 x 16      = 204800
#define WHB_OFF  466944                  // Wh:   100 x 4 x 128 x 128 = 6553600 (swizzled)
#define WMU_OFF  7020544                 // Wmu:  100 x 128           = 12800
#define WSG_OFF  7033344                 // Wsig: 100 x 128           = 12800
#define WS_ELEMS 7046144                 // *2 bytes = 14,092,288 B

// segment boundaries in 8-element groups
#define GX   32768                       // x
#define GW1  (GX + 25600)                // 58368
#define GWH  (GW1 + 819200)              // 877568
#define GMU  (GWH + 1600)                // 879168
#define GTOT (GMU + 1600)                // 880768

__global__ __launch_bounds__(256) void cvt_weights(
    const float* __restrict__ x,   const float* __restrict__ W1,
    const float* __restrict__ Wh,  const float* __restrict__ Wmu,
    const float* __restrict__ Wsg, unsigned short* __restrict__ ws)
{
  int gid = blockIdx.x * 256 + threadIdx.x;
  if (gid >= GTOT) return;
  const float* src;
  unsigned int dst;
  if (gid < GX) {
    src = x + gid * 8;                       dst = XB_OFF + gid * 8;
  } else if (gid < GW1) {
    int g = gid - GX;
    src = W1 + g * 8;                        dst = W1B_OFF + g * 8;
  } else if (gid < GWH) {
    int g = gid - GW1;
    int chunk  = g >> 11;                    // m*4 + layer (2048 groups/chunk)
    int within = g & 2047;
    int r    = within >> 4;                  // k_out row
    int col  = ((within & 15) * 8) ^ ((r & 7) << 3);  // swizzled 8-group
    src = Wh + (size_t)g * 8;
    dst = WHB_OFF + chunk * 16384 + r * HDIM + col;
  } else if (gid < GMU) {
    int g = gid - GWH;
    src = Wmu + g * 8;                       dst = WMU_OFF + g * 8;
  } else {
    int g = gid - GMU;
    src = Wsg + g * 8;                       dst = WSG_OFF + g * 8;
  }
  f32x4 a = *(const f32x4*)src;
  f32x4 b = *(const f32x4*)(src + 4);
  uint4 u;
  u.x = f2bf_pk(a[0], a[1]); u.y = f2bf_pk(a[2], a[3]);
  u.z = f2bf_pk(b[0], b[1]); u.w = f2bf_pk(b[2], b[3]);
  *(uint4*)&ws[dst] = u;
}

__device__ __forceinline__ void gload_lds16(const void* g, void* l) {
  __builtin_amdgcn_global_load_lds(
      (const __attribute__((address_space(1))) void*)g,
      (__attribute__((address_space(3))) void*)l, 16, 0, 0);
}

__global__ __launch_bounds__(256, 2) void ens_mlp(
    const unsigned short* __restrict__ ws,
    const float* __restrict__ b1,  const float* __restrict__ bh,
    const float* __restrict__ bmu, const float* __restrict__ bsg,
    float* __restrict__ out)
{
  __shared__ unsigned short hbuf[HDIM * HDIM]; // [n][h] bf16, swizzled
  __shared__ unsigned short wbuf[HDIM * HDIM]; // [k_out][h] bf16, swizzled

  // XCD-chunked bijective swizzle: 12800 blocks = 8 XCDs * 1600
  const int bid = blockIdx.x;
  const int swz = (bid & 7) * 1600 + (bid >> 3);
  const int m   = swz >> 7;            // model
  const int n0  = (swz & 127) << 7;    // batch-tile base

  const int t    = threadIdx.x;
  const int lane = t & 63;
  const int wv   = t >> 6;     // wave 0..3
  const int wk   = wv & 1;     // k_out half
  const int wn   = wv >> 1;    // n half
  const int c    = lane & 15;  // frag row (A: k_out, B: n) / D col (n)
  const int g    = lane >> 4;  // frag k-group / D row group
  const int cs   = (c & 7) << 3;  // xor swizzle term

  f32x4 zf = {0.0f, 0.0f, 0.0f, 0.0f};

  // ---- stage hidden-layer-0 weights into wbuf via global_load_lds --------
  {
    const char* wsrc = (const char*)(ws + WHB_OFF + m * 4 * 16384);
    char* wdst = (char*)wbuf;
    #pragma unroll
    for (int j = 0; j < 8; ++j) {
      int off = wv * 8192 + j * 1024 + lane * 16;
      gload_lds16(wsrc + off, wdst + off);
    }
  }

  // ---- layer 1: bf16 fragments direct from ws (K=16 zero-padded to 32) ---
  BF8 a1[4], xb4[4];
  {
    const unsigned short* W1m = ws + W1B_OFF + m * (HDIM * 16);
    const unsigned short* xbp = ws + XB_OFF;
    #pragma unroll
    for (int kt = 0; kt < 4; ++kt) {
      if (g < 2) {
        a1[kt].v = *(const bf16x8*)&W1m[(wk * 64 + kt * 16 + c) * 16 + g * 8];
      } else {
        a1[kt].ui[0] = 0u; a1[kt].ui[1] = 0u; a1[kt].ui[2] = 0u; a1[kt].ui[3] = 0u;
      }
    }
    #pragma unroll
    for (int nt = 0; nt < 4; ++nt) {
      if (g < 2) {
        xb4[nt].v = *(const bf16x8*)&xbp[(n0 + wn * 64 + nt * 16 + c) * 16 + g * 8];
      } else {
        xb4[nt].ui[0] = 0u; xb4[nt].ui[1] = 0u; xb4[nt].ui[2] = 0u; xb4[nt].ui[3] = 0u;
      }
    }
  }

  f32x4 bs[4];
  #pragma unroll
  for (int kt = 0; kt < 4; ++kt)
    bs[kt] = *(const f32x4*)(b1 + m * HDIM + (wk * 4 + kt) * 16 + g * 4);

  f32x4 acc[4][4];
  #pragma unroll
  for (int kt = 0; kt < 4; ++kt)
    #pragma unroll
    for (int nt = 0; nt < 4; ++nt)
      acc[kt][nt] = __builtin_amdgcn_mfma_f32_16x16x32_bf16(a1[kt].v, xb4[nt].v, zf, 0, 0, 0);

  // layer-1 epilogue: bias+relu+cvt -> hbuf
  #pragma unroll
  for (int kt = 0; kt < 4; ++kt) {
    int col = ((wk * 4 + kt) * 16 + g * 4) ^ cs;
    #pragma unroll
    for (int nt = 0; nt < 4; ++nt) {
      int nl = wn * 64 + nt * 16 + c;
      float v0 = fmaxf(acc[kt][nt][0] + bs[kt][0], 0.0f);
      float v1 = fmaxf(acc[kt][nt][1] + bs[kt][1], 0.0f);
      float v2 = fmaxf(acc[kt][nt][2] + bs[kt][2], 0.0f);
      float v3 = fmaxf(acc[kt][nt][3] + bs[kt][3], 0.0f);
      uint2 pk; pk.x = f2bf_pk(v0, v1); pk.y = f2bf_pk(v2, v3);
      *(uint2*)&hbuf[nl * HDIM + col] = pk;
    }
  }
  __syncthreads();   // drains gload_lds (vmcnt) + hbuf writes

  // ---------------- 4 hidden layers, in-place h and W ----------------------
  for (int i = 0; i < 4; ++i) {
    #pragma unroll
    for (int kt = 0; kt < 4; ++kt)
      bs[kt] = *(const f32x4*)(bh + m * 512 + i * HDIM + (wk * 4 + kt) * 16 + g * 4);

    #pragma unroll
    for (int kt = 0; kt < 4; ++kt)
      #pragma unroll
      for (int nt = 0; nt < 4; ++nt)
        acc[kt][nt] = zf;

    #pragma unroll
    for (int kc = 0; kc < 4; ++kc) {
      int col = (kc * 32 + g * 8) ^ cs;
      BF8 af[4], bf[4];
      #pragma unroll
      for (int kt = 0; kt < 4; ++kt)
        af[kt].v = *(const bf16x8*)&wbuf[(wk * 64 + kt * 16 + c) * HDIM + col];
      #pragma unroll
      for (int nt = 0; nt < 4; ++nt)
        bf[nt].v = *(const bf16x8*)&hbuf[(wn * 64 + nt * 16 + c) * HDIM + col];
      #pragma unroll
      for (int kt = 0; kt < 4; ++kt)
        #pragma unroll
        for (int nt = 0; nt < 4; ++nt)
          acc[kt][nt] = __builtin_amdgcn_mfma_f32_16x16x32_bf16(af[kt].v, bf[nt].v, acc[kt][nt], 0, 0, 0);
    }
    __syncthreads();   // all LDS reads of this layer done

    if (i < 3) {  // DMA next layer's (pre-swizzled) weights into wbuf
      const char* wsrc = (const char*)(ws + WHB_OFF + (m * 4 + i + 1) * 16384);
      char* wdst = (char*)wbuf;
      #pragma unroll
      for (int j = 0; j < 8; ++j) {
        int off = wv * 8192 + j * 1024 + lane * 16;
        gload_lds16(wsrc + off, wdst + off);
      }
    }

    // epilogue: write h in place
    #pragma unroll
    for (int kt = 0; kt < 4; ++kt) {
      int col = ((wk * 4 + kt) * 16 + g * 4) ^ cs;
      #pragma unroll
      for (int nt = 0; nt < 4; ++nt) {
        int nl = wn * 64 + nt * 16 + c;
        float v0 = fmaxf(acc[kt][nt][0] + bs[kt][0], 0.0f);
        float v1 = fmaxf(acc[kt][nt][1] + bs[kt][1], 0.0f);
        float v2 = fmaxf(acc[kt][nt][2] + bs[kt][2], 0.0f);
        float v3 = fmaxf(acc[kt][nt][3] + bs[kt][3], 0.0f);
        uint2 pk; pk.x = f2bf_pk(v0, v1); pk.y = f2bf_pk(v2, v3);
        *(uint2*)&hbuf[nl * HDIM + col] = pk;
      }
    }
    __syncthreads();   // drains vmcnt (weight DMA) + lgkm (h writes)
  }

  // ---------------- heads: mu and log-sigma -------------------------------
  f32x4 acc2[2];
  acc2[0] = zf; acc2[1] = zf;
  #pragma unroll
  for (int kc = 0; kc < 4; ++kc) {
    int col = (kc * 32 + g * 8) ^ cs;
    BF8 hw;
    if (c < 2) {
      const unsigned short* wp = ws + (c == 0 ? WMU_OFF : WSG_OFF) + m * HDIM + kc * 32 + g * 8;
      hw.v = *(const bf16x8*)wp;
    } else {
      hw.ui[0] = 0u; hw.ui[1] = 0u; hw.ui[2] = 0u; hw.ui[3] = 0u;
    }
    #pragma unroll
    for (int nt = 0; nt < 2; ++nt) {
      int nl = (wv * 2 + nt) * 16 + c;
      BF8 hf; hf.v = *(const bf16x8*)&hbuf[nl * HDIM + col];
      acc2[nt] = __builtin_amdgcn_mfma_f32_16x16x32_bf16(hw.v, hf.v, acc2[nt], 0, 0, 0);
    }
  }
  if (g == 0) {
    float bm  = bmu[m];
    float bsv = bsg[m];
    #pragma unroll
    for (int nt = 0; nt < 2; ++nt) {
      int n = n0 + (wv * 2 + nt) * 16 + c;
      out[m * NPT + n]          = acc2[nt][0] + bm;
      out[SG_OFF + m * NPT + n] = expf(acc2[nt][1] + bsv);
    }
  }
}

extern "C" void kernel_launch(void* const* d_in, const int* in_sizes, int n_in,
                              void* d_out, int out_size, void* d_ws, size_t ws_size,
                              hipStream_t stream) {
  const float* x   = (const float*)d_in[0];
  const float* W1  = (const float*)d_in[1];
  const float* b1  = (const float*)d_in[2];
  const float* Wh  = (const float*)d_in[3];
  const float* bh  = (const float*)d_in[4];
  const float* Wmu = (const float*)d_in[5];
  const float* bmu = (const float*)d_in[6];
  const float* Wsg = (const float*)d_in[7];
  const float* bsg = (const float*)d_in[8];
  unsigned short* ws = (unsigned short*)d_ws;
  (void)in_sizes; (void)n_in; (void)out_size; (void)ws_size;

  cvt_weights<<<(GTOT + 255) / 256, 256, 0, stream>>>(x, W1, Wh, Wmu, Wsg, ws);
  ens_mlp<<<12800, 256, 0, stream>>>(ws, b1, bh, bmu, bsg, (float*)d_out);
}

// Round 3
// 295.354 us; speedup vs baseline: 1.4099x; 1.1068x over previous
//
#include <hip/hip_runtime.h>

// BootstrapEnsemble: M=100 MLPs (16 -> 128 -> 4x(128x128) -> {mu, log sigma}),
// shared batch N=16384.
//  1) cvt_weights: one-shot fp32->bf16 (linear, row-major) of x/W1/Wh/Wmu/Wsig
//     into d_ws.
//  2) ens_mlp: fused MFMA MLP. Block = (model, 256-row n-chunk), 4 waves 2x2,
//     2 sequential 128-n subtiles. W fragments live in REGISTERS (loaded
//     straight from L2-hot global once per layer per wave); LDS holds only the
//     256x128 bf16 h tile (64 KB -> 2 blocks/CU). Swapped-operand
//     mfma_16x16x32_bf16; bias rides in the MFMA C operand; h epilogue uses
//     native cvt_pk. LDS XOR swizzle: col ^= (row&15)<<3.

typedef float  f32x4  __attribute__((ext_vector_type(4)));
typedef __bf16 bf16x4 __attribute__((ext_vector_type(4)));
typedef __bf16 bf16x8 __attribute__((ext_vector_type(8)));

union BF8 { bf16x8 v; unsigned int ui[4]; };
union BF4 { bf16x4 v; uint2 u2; };

#define MODELS 100
#define NPT    16384
#define HDIM   128
#define SG_OFF (MODELS * NPT)

// d_ws layout (bf16 element offsets), all row-major / linear
#define XB_OFF   0                       // x:    16384 x 16
#define W1B_OFF  262144                  // W1:   100 x 128 x 16
#define WHB_OFF  466944                  // Wh:   100 x 4 x 128 x 128
#define WMU_OFF  7020544                 // Wmu:  100 x 128
#define WSG_OFF  7033344                 // Wsig: 100 x 128

#define GTOT 880768                      // total 8-elem groups

__global__ __launch_bounds__(256) void cvt_weights(
    const float* __restrict__ x,   const float* __restrict__ W1,
    const float* __restrict__ Wh,  const float* __restrict__ Wmu,
    const float* __restrict__ Wsg, unsigned short* __restrict__ ws)
{
  int gid = blockIdx.x * 256 + threadIdx.x;
  if (gid >= GTOT) return;
  const float* src;
  unsigned int dst;
  if (gid < 32768)       { src = x   + gid * 8;                 dst = XB_OFF  + gid * 8; }
  else if (gid < 58368)  { int q = gid - 32768;  src = W1  + q * 8;          dst = W1B_OFF + q * 8; }
  else if (gid < 877568) { int q = gid - 58368;  src = Wh  + (size_t)q * 8;  dst = WHB_OFF + q * 8; }
  else if (gid < 879168) { int q = gid - 877568; src = Wmu + q * 8;          dst = WMU_OFF + q * 8; }
  else                   { int q = gid - 879168; src = Wsg + q * 8;          dst = WSG_OFF + q * 8; }
  f32x4 a = *(const f32x4*)src;
  f32x4 b = *(const f32x4*)(src + 4);
  BF4 lo, hi;
  lo.v = __builtin_convertvector(a, bf16x4);
  hi.v = __builtin_convertvector(b, bf16x4);
  uint4 u; u.x = lo.u2.x; u.y = lo.u2.y; u.z = hi.u2.x; u.w = hi.u2.y;
  *(uint4*)&ws[dst] = u;
}

__global__ __launch_bounds__(256, 2) void ens_mlp(
    const unsigned short* __restrict__ ws,
    const float* __restrict__ b1,  const float* __restrict__ bh,
    const float* __restrict__ bmu, const float* __restrict__ bsg,
    float* __restrict__ out)
{
  __shared__ unsigned short hbuf[256 * HDIM]; // [n 0..255][h 0..127] bf16, swizzled

  // XCD-chunked bijective swizzle: 6400 blocks = 8 XCDs * 800
  const int bid = blockIdx.x;
  const int swz = (bid & 7) * 800 + (bid >> 3);
  const int m   = swz >> 6;            // model 0..99
  const int n0  = (swz & 63) << 8;     // 256-row chunk base

  const int t    = threadIdx.x;
  const int lane = t & 63;
  const int wv   = t >> 6;     // wave 0..3
  const int wk   = wv & 1;     // k_out half
  const int wn   = wv >> 1;    // n half
  const int c    = lane & 15;  // frag row (A: k_out, B: n) / D col (n)
  const int g    = lane >> 4;  // frag k-group / D row group
  const int cs   = c << 3;     // xor swizzle ((row&15)<<3)

  const f32x4 zf = {0.0f, 0.0f, 0.0f, 0.0f};

  f32x4 acc[2][4][4];   // [subtile][kt][nt]

  // ---------------- layer 1 (K=16 zero-padded to 32) -----------------------
  {
    const unsigned short* W1m = ws + W1B_OFF + m * (HDIM * 16);
    const unsigned short* xbp = ws + XB_OFF;
    BF8 a1[4];
    #pragma unroll
    for (int kt = 0; kt < 4; ++kt) {
      if (g < 2) {
        a1[kt].v = *(const bf16x8*)&W1m[(wk * 64 + kt * 16 + c) * 16 + g * 8];
      } else {
        a1[kt].ui[0] = 0u; a1[kt].ui[1] = 0u; a1[kt].ui[2] = 0u; a1[kt].ui[3] = 0u;
      }
    }
    f32x4 bs[4];
    #pragma unroll
    for (int kt = 0; kt < 4; ++kt)
      bs[kt] = *(const f32x4*)(b1 + m * HDIM + (wk * 4 + kt) * 16 + g * 4);

    #pragma unroll
    for (int s = 0; s < 2; ++s) {
      BF8 xb[4];
      #pragma unroll
      for (int nt = 0; nt < 4; ++nt) {
        if (g < 2) {
          xb[nt].v = *(const bf16x8*)&xbp[(n0 + s * 128 + wn * 64 + nt * 16 + c) * 16 + g * 8];
        } else {
          xb[nt].ui[0] = 0u; xb[nt].ui[1] = 0u; xb[nt].ui[2] = 0u; xb[nt].ui[3] = 0u;
        }
      }
      #pragma unroll
      for (int kt = 0; kt < 4; ++kt)
        #pragma unroll
        for (int nt = 0; nt < 4; ++nt)
          acc[s][kt][nt] = __builtin_amdgcn_mfma_f32_16x16x32_bf16(a1[kt].v, xb[nt].v, bs[kt], 0, 0, 0);
    }
    // epilogue: relu + cvt -> hbuf
    #pragma unroll
    for (int s = 0; s < 2; ++s)
      #pragma unroll
      for (int kt = 0; kt < 4; ++kt) {
        int col = (((wk * 4 + kt) * 16 + g * 4)) ^ cs;
        #pragma unroll
        for (int nt = 0; nt < 4; ++nt) {
          int row = s * 128 + wn * 64 + nt * 16 + c;
          f32x4 v = __builtin_elementwise_max(acc[s][kt][nt], zf);
          BF4 b; b.v = __builtin_convertvector(v, bf16x4);
          *(uint2*)&hbuf[row * HDIM + col] = b.u2;
        }
      }
  }
  __syncthreads();

  // ---------------- 4 hidden layers ----------------------------------------
  for (int i = 0; i < 4; ++i) {
    // W fragments: straight from global (L2-hot), register-resident
    const unsigned short* whm = ws + WHB_OFF + (size_t)(m * 4 + i) * (HDIM * HDIM);
    BF8 af[4][4];   // [kt][kc]
    #pragma unroll
    for (int kt = 0; kt < 4; ++kt)
      #pragma unroll
      for (int kc = 0; kc < 4; ++kc)
        af[kt][kc].v = *(const bf16x8*)&whm[(wk * 64 + kt * 16 + c) * HDIM + kc * 32 + g * 8];

    {
      f32x4 bs[4];
      #pragma unroll
      for (int kt = 0; kt < 4; ++kt)
        bs[kt] = *(const f32x4*)(bh + m * 512 + i * HDIM + (wk * 4 + kt) * 16 + g * 4);
      #pragma unroll
      for (int s = 0; s < 2; ++s)
        #pragma unroll
        for (int kt = 0; kt < 4; ++kt)
          #pragma unroll
          for (int nt = 0; nt < 4; ++nt)
            acc[s][kt][nt] = bs[kt];
    }

    #pragma unroll
    for (int s = 0; s < 2; ++s)
      #pragma unroll
      for (int kc = 0; kc < 4; ++kc) {
        BF8 bf[4];
        #pragma unroll
        for (int nt = 0; nt < 4; ++nt)
          bf[nt].v = *(const bf16x8*)&hbuf[(s * 128 + wn * 64 + nt * 16 + c) * HDIM + ((kc * 32 + g * 8) ^ cs)];
        #pragma unroll
        for (int kt = 0; kt < 4; ++kt)
          #pragma unroll
          for (int nt = 0; nt < 4; ++nt)
            acc[s][kt][nt] = __builtin_amdgcn_mfma_f32_16x16x32_bf16(af[kt][kc].v, bf[nt].v, acc[s][kt][nt], 0, 0, 0);
      }
    __syncthreads();   // all h reads of this layer done

    // epilogue: relu + cvt, write h in place
    #pragma unroll
    for (int s = 0; s < 2; ++s)
      #pragma unroll
      for (int kt = 0; kt < 4; ++kt) {
        int col = (((wk * 4 + kt) * 16 + g * 4)) ^ cs;
        #pragma unroll
        for (int nt = 0; nt < 4; ++nt) {
          int row = s * 128 + wn * 64 + nt * 16 + c;
          f32x4 v = __builtin_elementwise_max(acc[s][kt][nt], zf);
          BF4 b; b.v = __builtin_convertvector(v, bf16x4);
          *(uint2*)&hbuf[row * HDIM + col] = b.u2;
        }
      }
    __syncthreads();
  }

  // ---------------- heads: mu (row 0) and log-sigma (row 1) ----------------
  {
    float bm  = bmu[m];
    float bsv = bsg[m];
    f32x4 acc2[2][2];   // [subtile][nt]
    #pragma unroll
    for (int s = 0; s < 2; ++s)
      #pragma unroll
      for (int nt = 0; nt < 2; ++nt) {
        acc2[s][nt] = zf;
        acc2[s][nt][0] = bm;
        acc2[s][nt][1] = bsv;
      }
    #pragma unroll
    for (int kc = 0; kc < 4; ++kc) {
      BF8 hw;
      if (c < 2) {
        const unsigned short* wp = ws + (c == 0 ? WMU_OFF : WSG_OFF) + m * HDIM + kc * 32 + g * 8;
        hw.v = *(const bf16x8*)wp;
      } else {
        hw.ui[0] = 0u; hw.ui[1] = 0u; hw.ui[2] = 0u; hw.ui[3] = 0u;
      }
      #pragma unroll
      for (int s = 0; s < 2; ++s)
        #pragma unroll
        for (int nt = 0; nt < 2; ++nt) {
          int nl = s * 128 + (wv * 2 + nt) * 16 + c;
          BF8 hf; hf.v = *(const bf16x8*)&hbuf[nl * HDIM + ((kc * 32 + g * 8) ^ cs)];
          acc2[s][nt] = __builtin_amdgcn_mfma_f32_16x16x32_bf16(hw.v, hf.v, acc2[s][nt], 0, 0, 0);
        }
    }
    if (g == 0) {
      #pragma unroll
      for (int s = 0; s < 2; ++s)
        #pragma unroll
        for (int nt = 0; nt < 2; ++nt) {
          int n = n0 + s * 128 + (wv * 2 + nt) * 16 + c;
          out[m * NPT + n]          = acc2[s][nt][0];
          out[SG_OFF + m * NPT + n] = expf(acc2[s][nt][1]);
        }
    }
  }
}

extern "C" void kernel_launch(void* const* d_in, const int* in_sizes, int n_in,
                              void* d_out, int out_size, void* d_ws, size_t ws_size,
                              hipStream_t stream) {
  const float* x   = (const float*)d_in[0];
  const float* W1  = (const float*)d_in[1];
  const float* b1  = (const float*)d_in[2];
  const float* Wh  = (const float*)d_in[3];
  const float* bh  = (const float*)d_in[4];
  const float* Wmu = (const float*)d_in[5];
  const float* bmu = (const float*)d_in[6];
  const float* Wsg = (const float*)d_in[7];
  const float* bsg = (const float*)d_in[8];
  unsigned short* ws = (unsigned short*)d_ws;
  (void)in_sizes; (void)n_in; (void)out_size; (void)ws_size;

  cvt_weights<<<(GTOT + 255) / 256, 256, 0, stream>>>(x, W1, Wh, Wmu, Wsg, ws);
  ens_mlp<<<6400, 256, 0, stream>>>(ws, b1, bh, bmu, bsg, (float*)d_out);
}